// Round 4
// baseline (95.693 us; speedup 1.0000x reference)
//
#include <hip/hip_runtime.h>
#include <hip/hip_bf16.h>

// Sizes (fixed by the problem)
#define NS   4096      // samples
#define NV   256       // variables/channels
#define NHID 64        // hidden
#define K2F  2.8853900817779268f   // 2*log2(e)

typedef short s8v __attribute__((ext_vector_type(8)));
typedef float f4v __attribute__((ext_vector_type(4)));

__device__ __forceinline__ unsigned short f2bf(float x) {
    __hip_bfloat16 h = __float2bfloat16(x);
    return *reinterpret_cast<unsigned short*>(&h);
}

// ---- prep: W2t[col][k] = adj[k,c] * w_in[c, k-(k>c), h],  col = c*64+h ----
__global__ __launch_bounds__(256) void k_prep_w2t(const float* __restrict__ adj,
                                                  const float* __restrict__ w_in,
                                                  unsigned short* __restrict__ W2t) {
    __shared__ float t[64][65];
    int c  = blockIdx.x >> 2;
    int k0 = (blockIdx.x & 3) * 64;
    int tid = threadIdx.x;
#pragma unroll
    for (int i = 0; i < 16; ++i) {
        int lin = i * 256 + tid;
        int kr = lin >> 6, h = lin & 63;
        int k = k0 + kr;
        float v = 0.0f;
        if (k != c) {
            int m = k - (k > c ? 1 : 0);
            v = adj[k * NV + c] * w_in[((size_t)c * 255 + m) * 64 + h];
        }
        t[kr][h] = v;
    }
    __syncthreads();
#pragma unroll
    for (int i = 0; i < 16; ++i) {
        int lin = i * 256 + tid;
        int h = lin >> 6, kr = lin & 63;
        W2t[((size_t)(c * 64 + h)) * NV + k0 + kr] = f2bf(t[kr][h]);
    }
}

// ---- prep (fused): data->bf16, out0=adj copy, g2/BO, bi2 ----
__global__ __launch_bounds__(256) void k_prep_small(
        const float* __restrict__ data, unsigned short* __restrict__ dataB,
        const float* __restrict__ adj,  float* __restrict__ out0,
        const float* __restrict__ neurons, const float* __restrict__ w_out,
        const float* __restrict__ b_out, float* __restrict__ g2, float* __restrict__ BO,
        const float* __restrict__ b_in, float* __restrict__ bi2)
{
    const int b = blockIdx.x, tid = threadIdx.x;
    if (b < 1024) {                       // data f32 -> bf16 (262144 float4)
        int i = b * 256 + tid;
        float4 v = reinterpret_cast<const float4*>(data)[i];
        ushort4 o = make_ushort4(f2bf(v.x), f2bf(v.y), f2bf(v.z), f2bf(v.w));
        reinterpret_cast<ushort4*>(dataB)[i] = o;
    } else if (b < 1088) {                // out0 = adj (16384 float4)
        int i = (b - 1024) * 256 + tid;
        reinterpret_cast<float4*>(out0)[i] = reinterpret_cast<const float4*>(adj)[i];
    } else if (b < 1152) {                // g2[j] = 2*neurons[h,c]*w_out[j]; BO[c]=b_out[c]+sum_h g
        int j = (b - 1088) * 256 + tid;
        int c = j >> 6, h = j & 63;
        float gv = neurons[h * NV + c] * w_out[j];
        g2[j] = 2.0f * gv;
        float s = gv;
        s += __shfl_xor(s, 1);  s += __shfl_xor(s, 2);  s += __shfl_xor(s, 4);
        s += __shfl_xor(s, 8);  s += __shfl_xor(s, 16); s += __shfl_xor(s, 32);
        if ((tid & 63) == 0) BO[c] = b_out[c] + s;
    } else {                              // bi2 = K2 * b_in (4096 float4)
        int i = (b - 1152) * 256 + tid;
        float4 v = reinterpret_cast<const float4*>(b_in)[i];
        v.x *= K2F; v.y *= K2F; v.z *= K2F; v.w *= K2F;
        reinterpret_cast<float4*>(bi2)[i] = v;
    }
}

// ---- main: no-LDS, no-barrier, all-register GEMM + fused tanh/gate/reduce.
// Each wave: m-strip of 64 rows (full K=256 of A in 128 VGPRs), 16 channels.
// B fragments stream global->VGPR with a 3-step prefetch window.
// Swapped MFMA operands: D rows = h, D cols = m  => h-sum is in-lane + 2 shfl.
__global__ __launch_bounds__(256, 1) void k_gemm_fused(
        const unsigned short* __restrict__ dataB,   // [4096][256] bf16
        const unsigned short* __restrict__ W2t,     // [16384][256] bf16
        const float* __restrict__ g2,               // [16384] 2*g
        const float* __restrict__ bi2,              // [16384] K2*b_in
        const float* __restrict__ BO,               // [256]  b_out + sum_h g
        float* __restrict__ out1)                   // [4096][256]
{
    const int tid  = threadIdx.x;
    const int w    = tid >> 6, lane = tid & 63;
    const int lq   = lane >> 4, lr = lane & 15;
    const int mstrip = (int)blockIdx.x >> 2;        // 64 m-strips
    const int ngrp   = (int)blockIdx.x & 3;         // 4 n-groups (XCD-friendly)
    const int m0     = mstrip * 64;
    const int cbase  = ngrp * 64 + w * 16;          // 16 channels per wave

    const s8v* Ab = (const s8v*)dataB;              // 16B units: row*32 + ks*4 + lq
    const s8v* Bb = (const s8v*)W2t;                // 16B units: col*32 + ks*4 + lq

    // A fragments, full K resident: a[mi][ks], lane lr = m-local row, lq = k-quarter
    s8v a[4][8];
#pragma unroll
    for (int mi = 0; mi < 4; ++mi)
#pragma unroll
        for (int ks = 0; ks < 8; ++ks)
            a[mi][ks] = Ab[(unsigned)(m0 + mi * 16 + lr) * 32u + ks * 4 + lq];

    // B prefetch window: 4 rotating groups of 4 fragments (hf = h-frag)
    s8v win[4][4];
#pragma unroll
    for (int j = 0; j < 3; ++j)                     // preload steps 0,1,2 (ch0,kk0..2)
#pragma unroll
        for (int hf = 0; hf < 4; ++hf)
            win[j][hf] = Bb[(unsigned)(cbase * 64 + hf * 16 + lr) * 32u + j * 4 + lq];

    for (int ch = 0; ch < 16; ++ch) {
        const int c = cbase + ch;

        // epilogue operands (issued early; consumed ~700 cyc later)
        float4 g2v[4], bi2v[4];
#pragma unroll
        for (int hf = 0; hf < 4; ++hf) {
            g2v[hf]  = *(const float4*)&g2 [c * 64 + hf * 16 + lq * 4];
            bi2v[hf] = *(const float4*)&bi2[c * 64 + hf * 16 + lq * 4];
        }
        const float BOv = BO[c];

        f4v acc[4][4];
#pragma unroll
        for (int kk = 0; kk < 8; ++kk) {
            // prefetch step kk+3 (wraps into next channel; tail overrun reads
            // stay inside d_ws scratch and are never consumed)
            {
                const int kk2 = (kk + 3) & 7;
                const int c2  = c + ((kk + 3) >> 3);
#pragma unroll
                for (int hf = 0; hf < 4; ++hf)
                    win[(kk + 3) & 3][hf] =
                        Bb[(unsigned)(c2 * 64 + hf * 16 + lr) * 32u + kk2 * 4 + lq];
            }
            // 16 MFMA, swapped operands: D[h-local][m-local]
#pragma unroll
            for (int mi = 0; mi < 4; ++mi)
#pragma unroll
                for (int hf = 0; hf < 4; ++hf) {
                    f4v cin = (kk == 0) ? (f4v){0.f, 0.f, 0.f, 0.f} : acc[mi][hf];
                    acc[mi][hf] = __builtin_amdgcn_mfma_f32_16x16x32_bf16(
                        win[kk & 3][hf], a[mi][kk], cin, 0, 0, 0);
                }
        }

        // Epilogue: per lane, h = hf*16 + lq*4 + r ; m = m0 + mi*16 + lr
        // out[m,c] = BO[c] - sum_h g2[h] * rcp(1 + exp2(K2*pre + bi2[h]))
        float s0, s1, s2, s3;
#define EPI_TERM(T, GC, BC, RR)                                                \
        { float mm = __builtin_fmaf(acc[mi][hf][RR], K2F, (BC));               \
          float e  = __builtin_amdgcn_exp2f(mm);                               \
          (T) = __builtin_fmaf((GC), __builtin_amdgcn_rcpf(e + 1.0f), (T)); }
#define EPI_MI(T)                                                              \
        { float t = 0.f;                                                       \
          _Pragma("unroll")                                                    \
          for (int hf = 0; hf < 4; ++hf) {                                     \
              EPI_TERM(t, g2v[hf].x, bi2v[hf].x, 0);                           \
              EPI_TERM(t, g2v[hf].y, bi2v[hf].y, 1);                           \
              EPI_TERM(t, g2v[hf].z, bi2v[hf].z, 2);                           \
              EPI_TERM(t, g2v[hf].w, bi2v[hf].w, 3);                           \
          }                                                                    \
          t += __shfl_xor(t, 16);                                              \
          t += __shfl_xor(t, 32);                                              \
          (T) = t; }
        { const int mi = 0; EPI_MI(s0); }
        { const int mi = 1; EPI_MI(s1); }
        { const int mi = 2; EPI_MI(s2); }
        { const int mi = 3; EPI_MI(s3); }
#undef EPI_MI
#undef EPI_TERM
        float v = lane < 16 ? s0 : (lane < 32 ? s1 : (lane < 48 ? s2 : s3));
        out1[(m0 + lane) * NV + c] = BOv - v;
    }
}

extern "C" void kernel_launch(void* const* d_in, const int* in_sizes, int n_in,
                              void* d_out, int out_size, void* d_ws, size_t ws_size,
                              hipStream_t stream) {
    const float* data    = (const float*)d_in[0];
    const float* adj     = (const float*)d_in[1];
    const float* neurons = (const float*)d_in[2];
    const float* w_in    = (const float*)d_in[3];
    const float* b_in    = (const float*)d_in[4];
    const float* w_out   = (const float*)d_in[5];
    const float* b_out   = (const float*)d_in[6];

    float* out0 = (float*)d_out;
    float* out1 = out0 + NV * NV;

    unsigned short* dataB = (unsigned short*)d_ws;                       // 2 MiB
    unsigned short* W2t   = (unsigned short*)((char*)d_ws + 2097152);    // 8 MiB
    float*          g2    = (float*)((char*)d_ws + 10485760);            // 64 KiB
    float*          bi2   = (float*)((char*)d_ws + 10551296);            // 64 KiB
    float*          BO    = (float*)((char*)d_ws + 10616832);            // 1 KiB

    hipLaunchKernelGGL(k_prep_w2t,   dim3(1024), dim3(256), 0, stream, adj, w_in, W2t);
    hipLaunchKernelGGL(k_prep_small, dim3(1168), dim3(256), 0, stream,
                       data, dataB, adj, out0, neurons, w_out, b_out, g2, BO, b_in, bi2);
    hipLaunchKernelGGL(k_gemm_fused, dim3(256), dim3(256), 0, stream,
                       dataB, W2t, g2, bi2, BO, out1);
}